// Round 13
// baseline (157.122 us; speedup 1.0000x reference)
//
#include <hip/hip_runtime.h>
#include <cstdint>
#include <cstddef>

typedef float f32x4 __attribute__((ext_vector_type(4)));
typedef short short8 __attribute__((ext_vector_type(8)));
typedef __bf16 bf16x8 __attribute__((ext_vector_type(8)));

__device__ __forceinline__ void mfma_bf16(f32x4& d, short8 a, short8 b){
  d = __builtin_amdgcn_mfma_f32_16x16x32_bf16(
        __builtin_bit_cast(bf16x8, a), __builtin_bit_cast(bf16x8, b), d, 0, 0, 0);
}

__device__ __forceinline__ unsigned short bf16_rn(float f){
  unsigned u = __float_as_uint(f);
  unsigned r = (u + 0x7FFF + ((u >> 16) & 1)) >> 16;
  return (unsigned short)r;
}

// 256-thread exclusive block scan (4 waves).
__device__ __forceinline__ int blockScan256Excl(int v, int* wsum){
  const int lane = threadIdx.x & 63, wv = threadIdx.x >> 6;
  int x = v;
  #pragma unroll
  for (int off = 1; off < 64; off <<= 1){
    int y = __shfl_up(x, off);
    if (lane >= off) x += y;
  }
  if (lane == 63) wsum[wv] = x;
  __syncthreads();
  int woff = 0;
  #pragma unroll
  for (int w = 0; w < 4; ++w) woff += (w < wv) ? wsum[w] : 0;
  return woff + x - v;
}

// ================= CSR build: two-level counting sort (no global atomics) =================
__global__ __launch_bounds__(256) void k_bcount(const int* __restrict__ dst, int E, int nb, int ntiles,
                                                int* __restrict__ blk_hist){
  __shared__ int h[256];
  const int tile = blockIdx.x;
  h[threadIdx.x] = 0;
  __syncthreads();
  const int base = tile * 2048;
  const int end = min(base + 2048, E);
  for (int i = base + threadIdx.x; i < end; i += 256)
    atomicAdd(&h[dst[i] >> 8], 1);
  __syncthreads();
  const int b = threadIdx.x;
  if (b < nb) blk_hist[(size_t)b * ntiles + tile] = h[b];
}

__global__ __launch_bounds__(256) void k_bscan(int* __restrict__ blk_hist, int nb, int ntiles,
                                               int* __restrict__ tot){
  __shared__ int wsum[4];
  __shared__ int carry;
  const int b = blockIdx.x;
  int* row = blk_hist + (size_t)b * ntiles;
  if (threadIdx.x == 0) carry = 0;
  __syncthreads();
  const int lane = threadIdx.x & 63, wv = threadIdx.x >> 6;
  for (int base = 0; base < ntiles; base += 256){
    const int i = base + threadIdx.x;
    const int v = (i < ntiles) ? row[i] : 0;
    int x = v;
    #pragma unroll
    for (int off = 1; off < 64; off <<= 1){
      int y = __shfl_up(x, off);
      if (lane >= off) x += y;
    }
    if (lane == 63) wsum[wv] = x;
    __syncthreads();
    int woff = 0;
    #pragma unroll
    for (int w = 0; w < 4; ++w) woff += (w < wv) ? wsum[w] : 0;
    const int incl = carry + woff + x;
    if (i < ntiles) row[i] = incl - v;
    __syncthreads();
    if (threadIdx.x == 255) carry = incl;
    __syncthreads();
  }
  if (threadIdx.x == 0) tot[b] = carry;
}

// k_btot folded into k_bscat / k_csrfin via redundant in-block scans of tot[196]

__global__ __launch_bounds__(256) void k_bscat(const int* __restrict__ src, const int* __restrict__ dst,
                                               int E, int nb, int ntiles,
                                               const int* __restrict__ blk_off,
                                               const int* __restrict__ tot,
                                               unsigned* __restrict__ ebuf){
  __shared__ int cnt[256];
  __shared__ int lofs[256];
  __shared__ int gbase[256];
  __shared__ unsigned sorted[2048];
  __shared__ unsigned char sb[2048];
  __shared__ int wsum[4];
  const int tile = blockIdx.x;
  cnt[threadIdx.x] = 0;
  __syncthreads();
  const int base = tile * 2048;
  const int end = min(base + 2048, E);
  const int m = end - base;

  int rank_[8]; int b_[8]; unsigned v_[8];
  #pragma unroll
  for (int k = 0; k < 8; ++k){
    const int j = threadIdx.x + k * 256;
    if (base + j < end){
      const int d = dst[base + j];
      const int s = src[base + j];
      const int b = d >> 8;
      b_[k] = b;
      v_[k] = ((unsigned)(d & 255) << 16) | (unsigned)s;
      rank_[k] = atomicAdd(&cnt[b], 1);
    } else b_[k] = -1;
  }
  __syncthreads();
  const int ex = blockScan256Excl(cnt[threadIdx.x], wsum);
  lofs[threadIdx.x] = ex;
  __syncthreads();
  // in-block bucket_base = excl-scan of tot
  const int tvv = (threadIdx.x < nb) ? tot[threadIdx.x] : 0;
  const int bb0 = blockScan256Excl(tvv, wsum);
  if (threadIdx.x < nb)
    gbase[threadIdx.x] = bb0 + blk_off[(size_t)threadIdx.x * ntiles + tile];
  __syncthreads();
  #pragma unroll
  for (int k = 0; k < 8; ++k){
    if (b_[k] >= 0){
      const int p = lofs[b_[k]] + rank_[k];
      sorted[p] = v_[k];
      sb[p] = (unsigned char)b_[k];
    }
  }
  __syncthreads();
  for (int j = threadIdx.x; j < m; j += 256){
    const int b = sb[j];
    ebuf[gbase[b] + (j - lofs[b])] = sorted[j];
  }
}

__global__ __launch_bounds__(256) void k_csrfin(const unsigned* __restrict__ ebuf,
                                                const int* __restrict__ tot,
                                                int n, int E, int nb,
                                                int* __restrict__ row_ptr,
                                                float* __restrict__ inv,
                                                unsigned short* __restrict__ csr){
  __shared__ int hist[256], cursor[256], bbs[257];
  __shared__ int wsum[4];
  __shared__ unsigned vals[8192];
  __shared__ unsigned short sorted[8192];
  const int b = blockIdx.x;
  const int t = threadIdx.x;
  // in-block bucket_base = excl-scan of tot
  const int tvv = (t < nb) ? tot[t] : 0;
  const int bb0 = blockScan256Excl(tvv, wsum);
  bbs[t] = bb0;
  if (t == 255) bbs[256] = bb0 + tvv;
  hist[t] = 0;
  __syncthreads();
  const int ebase = bbs[b];
  const int ecnt = bbs[b + 1] - ebase;
  for (int j = t; j < ecnt; j += 256){
    const unsigned v = ebuf[ebase + j];
    vals[j] = v;
    atomicAdd(&hist[v >> 16], 1);
  }
  __syncthreads();
  const int ex = blockScan256Excl(hist[t], wsum);
  cursor[t] = ex;
  const int node = b * 256 + t;
  if (node < n){
    row_ptr[node] = ebase + ex;
    const int c = hist[t];
    inv[node] = 1.0f / (float)(c > 0 ? c : 1);
  }
  if (b == nb - 1 && t == 0) row_ptr[n] = E;
  __syncthreads();
  for (int j = t; j < ecnt; j += 256){
    const unsigned v = vals[j];
    const int pos = atomicAdd(&cursor[v >> 16], 1);
    sorted[pos] = (unsigned short)(v & 0xFFFFu);
  }
  __syncthreads();
  for (int j = t; j < ecnt; j += 256)
    csr[ebase + j] = sorted[j];
}

// ================= fused prep: x->bf16 cvt | W1 pack | W2 pack | u vector =================
__device__ __forceinline__ void wcs_body(const float* __restrict__ wl, const float* __restrict__ wr,
                                         short* __restrict__ bfr, int id){
  if (id >= 128 * 256) return;
  int c = id >> 8, k = id & 255;
  float w = (k < 128) ? wl[c * 128 + k] : wr[c * 128 + (k - 128)];
  unsigned short h = bf16_rn(w);
  float hf = __uint_as_float((unsigned)h << 16);
  unsigned short l = bf16_rn(w - hf);
  const int nt = c >> 4, mrow = c & 15;
  const int ks = k >> 5, kgrp = (k >> 3) & 3, j = k & 7;
  const int lane = kgrp * 16 + mrow;
  const size_t fbase = (size_t)((ks * 8 + nt) * 2) * 512 + lane * 8 + j;
  bfr[fbase] = (short)h;
  bfr[fbase + 512] = (short)l;
}

__global__ __launch_bounds__(256) void k_prep(const float* __restrict__ x,
                                              unsigned short* __restrict__ xb, int n,
                                              const float* __restrict__ w1l, const float* __restrict__ w1r,
                                              short* __restrict__ bfr1,
                                              const float* __restrict__ w2l, const float* __restrict__ w2r,
                                              short* __restrict__ bfr2,
                                              const float* __restrict__ w3l, const float* __restrict__ w3r,
                                              const float* __restrict__ b3,
                                              const float* __restrict__ wp, const float* __restrict__ bp,
                                              float* __restrict__ u){
  const int nbcvt = (n * 128 / 4 + 255) / 256;
  const int b = blockIdx.x;
  if (b < nbcvt){
    const int i = (b * 256 + threadIdx.x) * 4;
    if (i < n * 128){
      const float4 v = *(const float4*)&x[i];
      ushort2 a, c;
      a.x = bf16_rn(v.x); a.y = bf16_rn(v.y);
      c.x = bf16_rn(v.z); c.y = bf16_rn(v.w);
      *(ushort2*)&xb[i] = a;
      *(ushort2*)&xb[i + 2] = c;
    }
  } else if (b < nbcvt + 128){
    wcs_body(w1l, w1r, bfr1, (b - nbcvt) * 256 + threadIdx.x);
  } else if (b < nbcvt + 256){
    wcs_body(w2l, w2r, bfr2, (b - nbcvt - 128) * 256 + threadIdx.x);
  } else {
    const int k = threadIdx.x;
    if (k < 128){
      float sl = 0.f, sr = 0.f;
      for (int o = 0; o < 64; ++o){
        float w = wp[o];
        sl = fmaf(w, w3l[o * 128 + k], sl);
        sr = fmaf(w, w3r[o * 128 + k], sr);
      }
      u[k] = sl; u[128 + k] = sr;
      if (k == 0){
        float c = bp[0];
        for (int o = 0; o < 64; ++o) c = fmaf(wp[o], b3[o], c);
        u[256] = c;
      }
    }
  }
}

// ---------------- mean aggregation: bf16 gather, fp32 accumulate, bf16 out ----------------
__global__ __launch_bounds__(256) void k_aggb(const unsigned short* __restrict__ featb,
                                              const unsigned short* __restrict__ csr,
                                              const int* __restrict__ row_ptr,
                                              const float* __restrict__ inv_cnt,
                                              unsigned short* __restrict__ outb, int n){
  const int lane = threadIdx.x & 63;
  const int node = (blockIdx.x * blockDim.x + threadIdx.x) >> 6;
  if (node >= n) return;
  const int beg = __builtin_amdgcn_readfirstlane(row_ptr[node]);
  const int end = __builtin_amdgcn_readfirstlane(row_ptr[node + 1]);
  const unsigned* __restrict__ fb = (const unsigned*)featb;   // [node][64]

  float axs[8] = {0,0,0,0,0,0,0,0};
  float ays[8] = {0,0,0,0,0,0,0,0};

  int j = beg;
  for (; j + 16 <= end; j += 16){
    unsigned uu[16];
    #pragma unroll
    for (int q = 0; q < 16; ++q) uu[q] = fb[(size_t)csr[j + q] * 64 + lane];
    #pragma unroll
    for (int q = 0; q < 16; ++q){
      axs[q & 7] += __uint_as_float(uu[q] << 16);
      ays[q & 7] += __uint_as_float(uu[q] & 0xFFFF0000u);
    }
  }
  if (j + 8 <= end){
    unsigned uu[8];
    #pragma unroll
    for (int q = 0; q < 8; ++q) uu[q] = fb[(size_t)csr[j + q] * 64 + lane];
    #pragma unroll
    for (int q = 0; q < 8; ++q){
      axs[q] += __uint_as_float(uu[q] << 16);
      ays[q] += __uint_as_float(uu[q] & 0xFFFF0000u);
    }
    j += 8;
  }
  if (j + 4 <= end){
    unsigned uu[4];
    #pragma unroll
    for (int q = 0; q < 4; ++q) uu[q] = fb[(size_t)csr[j + q] * 64 + lane];
    #pragma unroll
    for (int q = 0; q < 4; ++q){
      axs[q] += __uint_as_float(uu[q] << 16);
      ays[q] += __uint_as_float(uu[q] & 0xFFFF0000u);
    }
    j += 4;
  }
  for (; j < end; ++j){
    const unsigned u = fb[(size_t)csr[j] * 64 + lane];
    axs[4] += __uint_as_float(u << 16);
    ays[4] += __uint_as_float(u & 0xFFFF0000u);
  }

  const float ic = inv_cnt[node];
  const float ox = (((axs[0] + axs[1]) + (axs[2] + axs[3])) + ((axs[4] + axs[5]) + (axs[6] + axs[7]))) * ic;
  const float oy = (((ays[0] + ays[1]) + (ays[2] + ays[3])) + ((ays[4] + ays[5]) + (ays[6] + ays[7]))) * ic;
  const unsigned packed = (unsigned)bf16_rn(ox) | ((unsigned)bf16_rn(oy) << 16);
  ((unsigned*)outb)[(size_t)node * 64 + lane] = packed;
}

// ---------------- MFMA GEMM: prelu([A0|A1] @ W^T + b), 128 nodes/block, 32/wave ----------------
// Each wave computes 2 row-sub-tiles sharing each B-fragment load (halves B L2 traffic).
// Layer1 (out16 != null): write h1 bf16 row-major.
// Layer2 (uvec != null): fused head dot -> sbuf/pbuf (h2 never materialized).
__global__ __launch_bounds__(256) void k_gemm_mfma(const unsigned short* __restrict__ A0b,
                                                   const unsigned short* __restrict__ A1b,
                                                   const short* __restrict__ bfr,
                                                   const float* __restrict__ bias,
                                                   const float* __restrict__ alpha_p,
                                                   unsigned short* __restrict__ out16,  // or null
                                                   const float* __restrict__ uvec,      // or null
                                                   float* __restrict__ sbuf,
                                                   float* __restrict__ pbuf,
                                                   int n){
  __shared__ short aT[2][128 * 128];   // 2 tables x 128 rows x 256B, XOR-swizzled (64KB)
  const int t = threadIdx.x;
  const int lane = t & 63;
  const int wv = t >> 6;
  const int nodeBase = blockIdx.x * 128;

  #pragma unroll
  for (int tab = 0; tab < 2; ++tab){
    const unsigned short* __restrict__ src = tab ? A1b : A0b;
    #pragma unroll
    for (int it = 0; it < 8; ++it){
      const int chunk = it * 256 + t;       // 2048 chunks of 16B
      const int row = chunk >> 4;
      const int slot = chunk & 15;
      int gr = nodeBase + row; if (gr > n - 1) gr = n - 1;
      const uint4 v = *(const uint4*)&src[(size_t)gr * 128 + slot * 8];
      const int sslot = slot ^ (row & 7);
      *(uint4*)((char*)&aT[tab][0] + row * 256 + sslot * 16) = v;
    }
  }
  __syncthreads();

  const short8* __restrict__ Bf = (const short8*)bfr;
  const int mrow = lane & 15;
  const int kgrp = lane >> 4;
  const int arow0 = wv * 32 + mrow;
  const int arow1 = arow0 + 16;

  f32x4 acc[2][8];
  #pragma unroll
  for (int s = 0; s < 2; ++s)
    #pragma unroll
    for (int i = 0; i < 8; ++i) acc[s][i] = (f32x4){0.f, 0.f, 0.f, 0.f};

  #pragma unroll
  for (int ks = 0; ks < 8; ++ks){
    const int tab = ks >> 2;
    const int slot_r = (ks & 3) * 4 + kgrp;
    const short8 aF0 = *(const short8*)((const char*)&aT[tab][0] + arow0 * 256 + (slot_r ^ (arow0 & 7)) * 16);
    const short8 aF1 = *(const short8*)((const char*)&aT[tab][0] + arow1 * 256 + (slot_r ^ (arow1 & 7)) * 16);

    short8 bh[8], bl[8];
    const int fb = ks * 16;
    #pragma unroll
    for (int nt = 0; nt < 8; ++nt){
      bh[nt] = Bf[(size_t)(fb + nt * 2 + 0) * 64 + lane];
      bl[nt] = Bf[(size_t)(fb + nt * 2 + 1) * 64 + lane];
    }
    #pragma unroll
    for (int nt = 0; nt < 8; ++nt){
      mfma_bf16(acc[0][nt], aF0, bh[nt]);
      mfma_bf16(acc[0][nt], aF0, bl[nt]);
      mfma_bf16(acc[1][nt], aF1, bh[nt]);
      mfma_bf16(acc[1][nt], aF1, bl[nt]);
    }
  }

  const float alpha = *alpha_p;

  if (out16){
    #pragma unroll
    for (int s = 0; s < 2; ++s){
      const int nodeQ = nodeBase + wv * 32 + s * 16 + kgrp * 4;
      #pragma unroll
      for (int nt = 0; nt < 8; ++nt){
        const int col = nt * 16 + mrow;
        const float bv = bias[col];
        #pragma unroll
        for (int j = 0; j < 4; ++j){
          const int onode = nodeQ + j;
          if (onode < n){
            float v = acc[s][nt][j] + bv;
            v = fmaxf(v, 0.f) + alpha * fminf(v, 0.f);
            out16[(size_t)onode * 128 + col] = bf16_rn(v);
          }
        }
      }
    }
  } else {
    #pragma unroll
    for (int s = 0; s < 2; ++s){
      float sdot[4] = {0,0,0,0}, tdot[4] = {0,0,0,0};
      #pragma unroll
      for (int nt = 0; nt < 8; ++nt){
        const int col = nt * 16 + mrow;
        const float bv = bias[col];
        const float ul = uvec[col];
        const float ur = uvec[128 + col];
        #pragma unroll
        for (int j = 0; j < 4; ++j){
          float v = acc[s][nt][j] + bv;
          v = fmaxf(v, 0.f) + alpha * fminf(v, 0.f);
          sdot[j] = fmaf(v, ul, sdot[j]);
          tdot[j] = fmaf(v, ur, tdot[j]);
        }
      }
      #pragma unroll
      for (int j = 0; j < 4; ++j){
        #pragma unroll
        for (int off = 1; off < 16; off <<= 1){
          sdot[j] += __shfl_xor(sdot[j], off);
          tdot[j] += __shfl_xor(tdot[j], off);
        }
      }
      if (mrow == 0){
        const float c = uvec[256];
        const int nodeQ = nodeBase + wv * 32 + s * 16 + kgrp * 4;
        #pragma unroll
        for (int j = 0; j < 4; ++j){
          const int onode = nodeQ + j;
          if (onode < n){
            sbuf[onode] = sdot[j];
            pbuf[onode] = tdot[j] + c;
          }
        }
      }
    }
  }
}

__global__ __launch_bounds__(256) void k_final(const float* __restrict__ s, const float* __restrict__ partial,
                        const unsigned short* __restrict__ csr, const int* __restrict__ row_ptr,
                        const float* __restrict__ inv_cnt, float* __restrict__ out, int n){
  const int t = blockIdx.x * blockDim.x + threadIdx.x;
  const int node = t >> 2;
  const int sub = t & 3;
  if (node >= n) return;
  const int b = row_ptr[node], e = row_ptr[node + 1];
  float a0 = 0.f, a1 = 0.f;
  int j = b + sub;
  for (; j + 4 < e; j += 8){
    a0 += s[csr[j]];
    a1 += s[csr[j + 4]];
  }
  if (j < e) a0 += s[csr[j]];
  float acc = a0 + a1;
  acc += __shfl_down(acc, 1);
  acc += __shfl_down(acc, 2);
  if (sub == 0) out[node] = acc * inv_cnt[node] + partial[node];
}

// ---------------- launch ----------------
extern "C" void kernel_launch(void* const* d_in, const int* in_sizes, int n_in,
                              void* d_out, int out_size, void* d_ws, size_t ws_size,
                              hipStream_t stream){
  const float* x   = (const float*)d_in[0];
  const int*   ei  = (const int*)d_in[1];
  const float* w1l = (const float*)d_in[2];
  const float* w1r = (const float*)d_in[3];
  const float* b1  = (const float*)d_in[4];
  const float* w2l = (const float*)d_in[5];
  const float* w2r = (const float*)d_in[6];
  const float* b2  = (const float*)d_in[7];
  const float* w3l = (const float*)d_in[8];
  const float* w3r = (const float*)d_in[9];
  const float* b3  = (const float*)d_in[10];
  const float* ap  = (const float*)d_in[11];
  const float* wp  = (const float*)d_in[12];
  const float* bp  = (const float*)d_in[13];

  const int n = out_size;              // 50000 nodes
  const int E = in_sizes[1] / 2;       // 800000 edges
  const int* srcI = ei;
  const int* dstI = ei + E;

  const int ntiles = (E + 2047) / 2048;
  const int nb = (n + 255) >> 8;       // 196 buckets

  char* base = (char*)d_ws;
  size_t off = 0;
  auto take = [&](size_t bytes) -> char* {
    off = (off + 255) & ~(size_t)255;
    char* p = base + off;
    off += bytes;
    return p;
  };
  int*      blk_hist = (int*)   take((size_t)nb * ntiles * 4);
  int*      tot      = (int*)   take((size_t)nb * 4);
  unsigned* ebuf     = (unsigned*)take((size_t)E * 4);
  int*      rowp     = (int*)   take(((size_t)n + 1) * 4);
  float*    inv      = (float*) take((size_t)n * 4);
  unsigned short* csr = (unsigned short*)take((size_t)E * 2);
  unsigned short* B1b = (unsigned short*)take((size_t)n * 128 * 2);  // agg out, bf16
  unsigned short* xb  = (unsigned short*)take((size_t)n * 128 * 2);  // x bf16
  unsigned short* h1b = (unsigned short*)take((size_t)n * 128 * 2);  // h1 bf16
  float*    sbuf = (float*)take((size_t)n * 4);
  float*    pbuf = (float*)take((size_t)n * 4);
  float*    u    = (float*)take(257 * 4);
  short*    bfr1 = (short*)take((size_t)128 * 512 * 2);
  short*    bfr2 = (short*)take((size_t)128 * 512 * 2);
  (void)ws_size; (void)n_in;

  // CSR build: counting sort, no global atomics, coalesced writes
  k_bcount<<<ntiles, 256, 0, stream>>>(dstI, E, nb, ntiles, blk_hist);
  k_bscan <<<nb,     256, 0, stream>>>(blk_hist, nb, ntiles, tot);
  k_bscat <<<ntiles, 256, 0, stream>>>(srcI, dstI, E, nb, ntiles, blk_hist, tot, ebuf);
  k_csrfin<<<nb,     256, 0, stream>>>(ebuf, tot, n, E, nb, rowp, inv, csr);

  // fused prep: x->bf16 | W1 pack | W2 pack | u vector
  const int nbcvt = (n * 128 / 4 + 255) / 256;
  k_prep<<<nbcvt + 257, 256, 0, stream>>>(x, xb, n, w1l, w1r, bfr1, w2l, w2r, bfr2,
                                          w3l, w3r, b3, wp, bp, u);

  const int aggGrid  = (n * 64 + 255) / 256;
  const int gemmGrid = (n + 127) / 128;

  // layer 1: h1 = prelu([agg(x)|x] @ W1 + b1)  -> bf16
  k_aggb     <<<aggGrid, 256, 0, stream>>>(xb, csr, rowp, inv, B1b, n);
  k_gemm_mfma<<<gemmGrid, 256, 0, stream>>>(B1b, xb, bfr1, b1, ap, h1b,
                                            (const float*)nullptr, (float*)nullptr, (float*)nullptr, n);

  // layer 2: fused h2 GEMM + head dot -> sbuf/pbuf (h2 never materialized)
  k_aggb     <<<aggGrid, 256, 0, stream>>>(h1b, csr, rowp, inv, B1b, n);
  k_gemm_mfma<<<gemmGrid, 256, 0, stream>>>(B1b, h1b, bfr2, b2, ap, (unsigned short*)nullptr,
                                            u, sbuf, pbuf, n);

  // final: level = mean(s) + partial
  k_final<<<(n * 4 + 255) / 256, 256, 0, stream>>>(sbuf, pbuf, csr, rowp, inv, (float*)d_out, n);
}